// Round 13
// baseline (373.446 us; speedup 1.0000x reference)
//
#include <hip/hip_runtime.h>
#include <hip/hip_cooperative_groups.h>
#include <math.h>

namespace cg = cooperative_groups;

#define DM 128
#define SEQ 512
#define NTOK 2048
#define NH 8
#define HD 16
#define NE 256
#define CAP 4096
#define GRID 256
#define NTHR 512

__device__ __forceinline__ float sigmoid_f(float v) { return 1.0f / (1.0f + expf(-v)); }

__device__ __forceinline__ float wave_sum64(float v) {
#pragma unroll
  for (int m = 32; m; m >>= 1) v += __shfl_xor(v, m, 64);
  return v;
}

struct MegaP {
  const float *x, *g1, *wq, *bq, *wk, *bk, *wv, *bv, *wo, *bo, *rot, *tqs;
  const float *w1, *b1, *w2, *b2, *g2, *gw, *gb, *ew, *mw1, *mb1, *mw2, *mb2;
  float *q, *k, *v, *ctxp, *ksump, *xmid, *h2, *tw, *elbuf;
  int *cnt, *list;
  float *out_x, *out_c;
};

union SharedU {
  struct { float h1[4][DM]; float qr[4][DM]; float kr[4][DM]; float red3[4][4][DM][3]; } p1;  // 30.7KB
  struct { float part[2][256][2]; } p2;                                                       // 4KB
  struct { float ctxs[NH * 256]; float kss[DM]; float rowA[4][DM]; float rowB[4][DM];
           float red2[4][4][DM][2]; float redg[2][4][NE]; float lgl[4][NE]; } p3;             // 40.5KB
  struct { float h2t[8][DM]; float psum[4][8][DM]; int alst[8]; } p4;                         // 20KB
  struct { float was[4][DM]; } p5;                                                            // 2KB
};

// No-carry mega-kernel: exact r7 phase bodies; ALL inter-phase state flows
// through global buffers (q, xmid, tw, h2, ...) exactly as the 5-kernel
// pipeline does. Nothing live across grid.sync() except tid/bid derivatives.
__global__ __launch_bounds__(NTHR) void mega(MegaP p) {
  const int tid = threadIdx.x;
  const int bid = blockIdx.x;
  const int o = tid & 127, ks = tid >> 7;
  cg::grid_group grid = cg::this_grid();
  __shared__ SharedU su;
  __shared__ float wredA[8], wredB[8];

  if (bid == 0 && tid < NE) p.cnt[tid] = 0;

  // ============ Phase 1: rmsnorm + QKV + RoPE + elu+1 (2 halves x 4 tokens) ============
  for (int hh = 0; hh < 2; ++hh) {
    const int n0 = (bid * 2 + hh) * 4;
    __syncthreads();
    float xv = p.x[(n0 + ks) * DM + o];
    float s = wave_sum64(xv * xv);
    if ((tid & 63) == 0) wredA[tid >> 6] = s;
    __syncthreads();
    float tot = wredA[2 * ks] + wredA[2 * ks + 1];
    float rinv = 1.0f / sqrtf(tot * (1.0f / 128.0f) + 1e-6f);
    su.p1.h1[ks][o] = p.g1[o] * xv * rinv;
    __syncthreads();

    float aq[4] = {0, 0, 0, 0}, ak[4] = {0, 0, 0, 0}, av[4] = {0, 0, 0, 0};
    const int d0 = ks * 32;
    for (int dd = 0; dd < 32; ++dd) {
      int d = d0 + dd;
      float wqv = p.wq[d * DM + o], wkv = p.wk[d * DM + o], wvv = p.wv[d * DM + o];
#pragma unroll
      for (int g = 0; g < 4; ++g) {
        float hv = su.p1.h1[g][d];
        aq[g] = fmaf(hv, wqv, aq[g]);
        ak[g] = fmaf(hv, wkv, ak[g]);
        av[g] = fmaf(hv, wvv, av[g]);
      }
    }
#pragma unroll
    for (int g = 0; g < 4; ++g) {
      su.p1.red3[ks][g][o][0] = aq[g];
      su.p1.red3[ks][g][o][1] = ak[g];
      su.p1.red3[ks][g][o][2] = av[g];
    }
    __syncthreads();
    float sq = p.bq[o], sk = p.bk[o], sv = p.bv[o];
#pragma unroll
    for (int s2 = 0; s2 < 4; ++s2) {
      sq += su.p1.red3[s2][ks][o][0];
      sk += su.p1.red3[s2][ks][o][1];
      sv += su.p1.red3[s2][ks][o][2];
    }
    su.p1.qr[ks][o] = sq;
    su.p1.kr[ks][o] = sk;
    p.v[(n0 + ks) * DM + o] = sv;
    __syncthreads();

    const int i = o & 15, j = i & 7, hi = i & 8, lo = o & ~8;
    const float invf = expf(-(float)j * 1.1512925464970229f);  // ln(10000)/8
    int t = (n0 + ks) & (SEQ - 1);
    float ang = (float)t * invf;
    float sn = sinf(ang), cs = cosf(ang);
    float x1q = su.p1.qr[ks][lo], x2q = su.p1.qr[ks][lo + 8];
    float x1k = su.p1.kr[ks][lo], x2k = su.p1.kr[ks][lo + 8];
    float rqv = hi ? (x1q * sn + x2q * cs) : (x1q * cs - x2q * sn);
    float rkv = hi ? (x1k * sn + x2k * cs) : (x1k * cs - x2k * sn);
    rqv = (rqv > 0.0f) ? rqv + 1.0f : expf(rqv);
    rkv = (rkv > 0.0f) ? rkv + 1.0f : expf(rkv);
    p.q[(n0 + ks) * DM + o] = rqv;
    p.k[(n0 + ks) * DM + o] = rkv;
  }
  grid.sync();

  // ============ Phase 2: ctx/ksum partials (8 chunks x 32 bh, 2-way t-split) ============
  {
    const int tc = bid >> 5, bh = bid & 31;
    const int b2 = bh >> 3, h = bh & 7;
    const int sub = tid >> 8, pp = tid & 255, d = pp >> 4, e = pp & 15;
    const float* kb = p.k + (size_t)b2 * SEQ * DM + h * HD;
    const float* vb = p.v + (size_t)b2 * SEQ * DM + h * HD;
    float acc = 0.0f, kssv = 0.0f;
    for (int tt = 0; tt < 32; ++tt) {
      int t = tc * 64 + sub * 32 + tt;
      float kv = kb[t * DM + d];
      float vv = vb[t * DM + e];
      acc = fmaf(kv, vv, acc);
      kssv += kv;
    }
    su.p2.part[sub][pp][0] = acc;
    su.p2.part[sub][pp][1] = kssv;
    __syncthreads();
    if (tid < 256) {
      p.ctxp[tc * 8192 + bh * 256 + tid] = su.p2.part[0][tid][0] + su.p2.part[1][tid][0];
      if ((tid & 15) == 0)
        p.ksump[tc * 512 + bh * HD + (tid >> 4)] =
            su.p2.part[0][tid][1] + su.p2.part[1][tid][1];
    }
  }
  grid.sync();

  // ============ Phase 3: attn + wo + tq + swiglu + residual + rmsnorm + gate ============
  {
    const int b = bid >> 6;
    for (int idx = tid; idx < 2048; idx += NTHR) {
      float s = 0.0f;
#pragma unroll
      for (int tc = 0; tc < 8; ++tc) s += p.ctxp[tc * 8192 + b * 2048 + idx];
      su.p3.ctxs[idx] = s;
    }
    if (tid < 128) {
      float s = 0.0f;
#pragma unroll
      for (int tc = 0; tc < 8; ++tc) s += p.ksump[tc * 512 + b * DM + tid];
      su.p3.kss[tid] = s;
    }

    for (int hh = 0; hh < 2; ++hh) {
      const int n0 = (bid * 2 + hh) * 4;
      __syncthreads();
      su.p3.rowA[ks][o] = p.q[(n0 + ks) * DM + o];  // from global (no carry)
      __syncthreads();

      {
        int h = o >> 4, e = o & 15;
        float oa = 0.0f, qk = 0.0f;
#pragma unroll
        for (int d = 0; d < HD; ++d) {
          float qv = su.p3.rowA[ks][h * HD + d];
          oa = fmaf(qv, su.p3.ctxs[h * 256 + d * 16 + e], oa);
          qk = fmaf(qv, su.p3.kss[h * HD + d], qk);
        }
        su.p3.rowB[ks][o] = oa / (qk + 1e-6f);
      }
      __syncthreads();

      const int d0 = ks * 32;
      {
        float acc[4] = {0, 0, 0, 0};
        for (int dd = 0; dd < 32; ++dd) {
          int d = d0 + dd;
          float w = p.wo[d * DM + o];
#pragma unroll
          for (int g = 0; g < 4; ++g) acc[g] = fmaf(su.p3.rowB[g][d], w, acc[g]);
        }
#pragma unroll
        for (int g = 0; g < 4; ++g) su.p3.red2[ks][g][o][0] = acc[g];
      }
      __syncthreads();
      {
        float sa = p.bo[o];
#pragma unroll
        for (int s2 = 0; s2 < 4; ++s2) sa += su.p3.red2[s2][ks][o][0];
        su.p3.rowA[ks][o] = sa;
      }
      __syncthreads();

      {
        float acc[4] = {0, 0, 0, 0};
        for (int dd = 0; dd < 32; ++dd) {
          int d = d0 + dd;
          float r = p.rot[d * DM + o];
#pragma unroll
          for (int g = 0; g < 4; ++g) acc[g] = fmaf(su.p3.rowA[g][d], r, acc[g]);
        }
#pragma unroll
        for (int g = 0; g < 4; ++g) su.p3.red2[ks][g][o][1] = acc[g];
      }
      __syncthreads();
      {
        float y = 0.0f;
#pragma unroll
        for (int s2 = 0; s2 < 4; ++s2) y += su.p3.red2[s2][ks][o][1];
        float ssq = wave_sum64(y * y);
        if ((tid & 63) == 0) wredA[tid >> 6] = ssq;
        __syncthreads();
        float tot = wredA[2 * ks] + wredA[2 * ks + 1];
        float mag = sqrtf(tot * (1.0f / 128.0f) + 1e-6f);
        float phase = y / mag;
        su.p3.rowB[ks][o] = rintf(phase * 8.0f) * 0.125f * mag * p.tqs[o];
      }
      __syncthreads();

      {
        float a1[4] = {0, 0, 0, 0}, a2[4] = {0, 0, 0, 0};
        for (int dd = 0; dd < 32; ++dd) {
          int d = d0 + dd;
          float w1v = p.w1[d * DM + o];
          float w2v = p.w2[d * DM + o];
#pragma unroll
          for (int g = 0; g < 4; ++g) {
            float t = su.p3.rowB[g][d];
            a1[g] = fmaf(t, w1v, a1[g]);
            a2[g] = fmaf(t, w2v, a2[g]);
          }
        }
#pragma unroll
        for (int g = 0; g < 4; ++g) {
          su.p3.red2[ks][g][o][0] = a1[g];
          su.p3.red2[ks][g][o][1] = a2[g];
        }
      }
      __syncthreads();
      {
        float ga = p.b1[o], up = p.b2[o];
#pragma unroll
        for (int s2 = 0; s2 < 4; ++s2) {
          ga += su.p3.red2[s2][ks][o][0];
          up += su.p3.red2[s2][ks][o][1];
        }
        float swv = ga * sigmoid_f(ga) * up;
        float xmv = p.x[(n0 + ks) * DM + o] + swv;  // reload x (no carry)
        p.xmid[(n0 + ks) * DM + o] = xmv;
        float ssq = wave_sum64(xmv * xmv);
        if ((tid & 63) == 0) wredB[tid >> 6] = ssq;
        __syncthreads();
        float tot = wredB[2 * ks] + wredB[2 * ks + 1];
        float rinv = 1.0f / sqrtf(tot * (1.0f / 128.0f) + 1e-6f);
        float h2v = p.g2[o] * xmv * rinv;
        p.h2[(n0 + ks) * DM + o] = h2v;
        su.p3.rowA[ks][o] = h2v;
      }
      __syncthreads();

      // gate logits (2-way k-split)
      {
        int e = tid & 255, kq = tid >> 8;
        float lg[4] = {0, 0, 0, 0};
        for (int dd = 0; dd < 64; ++dd) {
          int d = kq * 64 + dd;
          float gwv = p.gw[d * NE + e];
#pragma unroll
          for (int g = 0; g < 4; ++g) lg[g] = fmaf(su.p3.rowA[g][d], gwv, lg[g]);
        }
#pragma unroll
        for (int g = 0; g < 4; ++g) su.p3.redg[kq][g][e] = lg[g];
      }
      __syncthreads();
      {
        int e = tid & 255, half = tid >> 8;
        float gbv = p.gb[e];
#pragma unroll
        for (int gg2 = 0; gg2 < 2; ++gg2) {
          int g = half * 2 + gg2;
          su.p3.lgl[g][e] = su.p3.redg[0][g][e] + su.p3.redg[1][g][e] + gbv;
        }
      }
      __syncthreads();

      if (tid < 256) {
        int lane = tid & 63, g = tid >> 6;
        float bv = -INFINITY;
        int bi = 0;
#pragma unroll
        for (int j2 = 0; j2 < 4; ++j2) {
          int e = lane + 64 * j2;
          float vv = su.p3.lgl[g][e];
          if (vv > bv || (vv == bv && e < bi)) { bv = vv; bi = e; }
        }
#pragma unroll
        for (int m = 32; m; m >>= 1) {
          float pv = __shfl_xor(bv, m, 64);
          int pi = __shfl_xor(bi, m, 64);
          if (pv > bv || (pv == bv && pi < bi)) { bv = pv; bi = pi; }
        }
        float se = 0.0f;
#pragma unroll
        for (int j2 = 0; j2 < 4; ++j2) se += expf(su.p3.lgl[g][lane + 64 * j2] - bv);
        se = wave_sum64(se);
        float mv = -INFINITY;
        int mi = 0;
#pragma unroll
        for (int j2 = 0; j2 < 4; ++j2) {
          int e = lane + 64 * j2;
          if (e != bi) {
            float vv = su.p3.lgl[g][e];
            if (vv > mv || (vv == mv && e < mi)) { mv = vv; mi = e; }
          }
        }
#pragma unroll
        for (int m = 32; m; m >>= 1) {
          float pv = __shfl_xor(mv, m, 64);
          int pi = __shfl_xor(mi, m, 64);
          if (pv > mv || (pv == mv && pi < mi)) { mv = pv; mi = pi; }
        }
        if (lane == 0) {
          float v0 = 1.0f / se;
          float v1 = expf(mv - bv) / se;
          float wsum = v0 + v1 + 1e-6f;
          int t = n0 + g;
          p.tw[t * 2 + 0] = v0 / wsum;   // to global (no carry)
          p.tw[t * 2 + 1] = v1 / wsum;
          int r0 = atomicAdd(&p.cnt[bi], 1);
          p.list[bi * CAP + r0] = t * 2 + 0;
          int r1 = atomicAdd(&p.cnt[mi], 1);
          p.list[mi * CAP + r1] = t * 2 + 1;
        }
      }
    }
  }
  grid.sync();

  // ============ Phase 4: expert-centric GEMVs (1 block/expert) ============
  {
    const int e = bid;
    const int nt = p.cnt[e];
    const int qq = tid >> 7;
    if (nt > 0) {
      const float* W = p.ew + (size_t)e * (DM * DM);
      float wreg[32];
#pragma unroll
      for (int dd = 0; dd < 32; ++dd) wreg[dd] = W[(qq * 32 + dd) * DM + o];
      for (int i0 = 0; i0 < nt; i0 += 8) {
        int gn = min(8, nt - i0);
        for (int idx = tid; idx < gn * 128; idx += NTHR) {
          int j = idx >> 7;
          int a = p.list[e * CAP + i0 + j];
          su.p4.h2t[j][idx & 127] = p.h2[(size_t)(a >> 1) * DM + (idx & 127)];
        }
        if (tid < gn) su.p4.alst[tid] = p.list[e * CAP + i0 + tid];
        __syncthreads();
        for (int j = 0; j < gn; ++j) {
          const float4* hp = (const float4*)&su.p4.h2t[j][qq * 32];
          float acc = 0.0f;
#pragma unroll
          for (int d4 = 0; d4 < 8; ++d4) {
            float4 hv = hp[d4];
            acc = fmaf(wreg[d4 * 4 + 0], hv.x, acc);
            acc = fmaf(wreg[d4 * 4 + 1], hv.y, acc);
            acc = fmaf(wreg[d4 * 4 + 2], hv.z, acc);
            acc = fmaf(wreg[d4 * 4 + 3], hv.w, acc);
          }
          su.p4.psum[qq][j][o] = acc;
        }
        __syncthreads();
        for (int j = qq; j < gn; j += 4) {
          float r = su.p4.psum[0][j][o] + su.p4.psum[1][j][o] +
                    su.p4.psum[2][j][o] + su.p4.psum[3][j][o];
          p.elbuf[(size_t)su.p4.alst[j] * DM + o] = r;
        }
        __syncthreads();
      }
    }
  }
  grid.sync();

  // ============ Phase 5: combine + swiglu + residual + consensus (2 halves) ============
  for (int hh = 0; hh < 2; ++hh) {
    const int n0 = (bid * 2 + hh) * 4;
    const int t = n0 + ks;
    __syncthreads();
    float w0 = p.tw[t * 2 + 0], w1 = p.tw[t * 2 + 1];  // from global (no carry)
    float el0 = p.elbuf[(size_t)(t * 2 + 0) * DM + o];
    float el1 = p.elbuf[(size_t)(t * 2 + 1) * DM + o];
    su.p5.was[ks][o] = w0 * el0 + w1 * el1;
    __syncthreads();
    float a1 = p.mb1[o], a2 = p.mb2[o];
    for (int d = 0; d < DM; ++d) {
      float tt = su.p5.was[ks][d];
      a1 = fmaf(tt, p.mw1[d * DM + o], a1);
      a2 = fmaf(tt, p.mw2[d * DM + o], a2);
    }
    float swv = a1 * sigmoid_f(a1) * a2;
    p.out_x[(size_t)t * DM + o] = p.xmid[(size_t)t * DM + o] + swv;  // reload xmid
    float dd0 = el0 - swv, dd1 = el1 - swv;
    float vt = wave_sum64(w0 * dd0 * dd0 + w1 * dd1 * dd1);
    if ((tid & 63) == 0) wredA[tid >> 6] = vt;
    __syncthreads();
    if (tid < 4)
      p.out_c[n0 + tid] = expf(-(wredA[2 * tid] + wredA[2 * tid + 1]) * (1.0f / 128.0f));
  }
}

// ==================== Fallback path: round-7 five-kernel pipeline (64.7 us, verified) ====================

__global__ __launch_bounds__(512) void k_qkv(
    const float* __restrict__ x, const float* __restrict__ g1,
    const float* __restrict__ wq, const float* __restrict__ bq,
    const float* __restrict__ wk, const float* __restrict__ bk,
    const float* __restrict__ wv, const float* __restrict__ bv_,
    float* __restrict__ q, float* __restrict__ k, float* __restrict__ v,
    int* __restrict__ cnt) {
  const int tid = threadIdx.x;
  const int o = tid & 127, ks = tid >> 7;
  const int n0 = blockIdx.x * 4;
  __shared__ float h1[4][DM];
  __shared__ float qr[4][DM], kr[4][DM];
  __shared__ float red3[4][4][DM][3];
  __shared__ float wredA[8];

  if (blockIdx.x == 0 && tid < NE) cnt[tid] = 0;

  float xv = x[(n0 + ks) * DM + o];
  float s = wave_sum64(xv * xv);
  if ((tid & 63) == 0) wredA[tid >> 6] = s;
  __syncthreads();
  float tot = wredA[2 * ks] + wredA[2 * ks + 1];
  float rinv = 1.0f / sqrtf(tot * (1.0f / 128.0f) + 1e-6f);
  h1[ks][o] = g1[o] * xv * rinv;
  __syncthreads();

  float aq[4] = {0, 0, 0, 0}, ak[4] = {0, 0, 0, 0}, av[4] = {0, 0, 0, 0};
  const int d0 = ks * 32;
  for (int dd = 0; dd < 32; ++dd) {
    int d = d0 + dd;
    float wqv = wq[d * DM + o], wkv = wk[d * DM + o], wvv = wv[d * DM + o];
#pragma unroll
    for (int g = 0; g < 4; ++g) {
      float hv = h1[g][d];
      aq[g] = fmaf(hv, wqv, aq[g]);
      ak[g] = fmaf(hv, wkv, ak[g]);
      av[g] = fmaf(hv, wvv, av[g]);
    }
  }
#pragma unroll
  for (int g = 0; g < 4; ++g) {
    red3[ks][g][o][0] = aq[g];
    red3[ks][g][o][1] = ak[g];
    red3[ks][g][o][2] = av[g];
  }
  __syncthreads();
  float sq = bq[o], sk = bk[o], sv = bv_[o];
#pragma unroll
  for (int s2 = 0; s2 < 4; ++s2) {
    sq += red3[s2][ks][o][0];
    sk += red3[s2][ks][o][1];
    sv += red3[s2][ks][o][2];
  }
  qr[ks][o] = sq;
  kr[ks][o] = sk;
  v[(n0 + ks) * DM + o] = sv;
  __syncthreads();

  const int i = o & 15, j = i & 7, hi = i & 8, lo = o & ~8;
  const float invf = expf(-(float)j * 1.1512925464970229f);
  int t = (n0 + ks) & (SEQ - 1);
  float ang = (float)t * invf;
  float sn = sinf(ang), cs = cosf(ang);
  float x1q = qr[ks][lo], x2q = qr[ks][lo + 8];
  float x1k = kr[ks][lo], x2k = kr[ks][lo + 8];
  float rq = hi ? (x1q * sn + x2q * cs) : (x1q * cs - x2q * sn);
  float rk = hi ? (x1k * sn + x2k * cs) : (x1k * cs - x2k * sn);
  rq = (rq > 0.0f) ? rq + 1.0f : expf(rq);
  rk = (rk > 0.0f) ? rk + 1.0f : expf(rk);
  q[(n0 + ks) * DM + o] = rq;
  k[(n0 + ks) * DM + o] = rk;
}

__global__ __launch_bounds__(256) void k_ctxp(
    const float* __restrict__ k, const float* __restrict__ v,
    float* __restrict__ ctxp, float* __restrict__ ksump) {
  const int bh = blockIdx.x & 31, tc = blockIdx.x >> 5;
  const int b = bh >> 3, h = bh & 7;
  const int p = threadIdx.x, d = p >> 4, e = p & 15;
  const float* kb = k + (size_t)b * SEQ * DM + h * HD;
  const float* vb = v + (size_t)b * SEQ * DM + h * HD;
  float acc = 0.0f, kss = 0.0f;
  for (int tt = 0; tt < 64; ++tt) {
    int t = tc * 64 + tt;
    float kv = kb[t * DM + d];
    float vv = vb[t * DM + e];
    acc = fmaf(kv, vv, acc);
    kss += kv;
  }
  ctxp[tc * 8192 + bh * 256 + p] = acc;
  if (e == 0) ksump[tc * 512 + bh * HD + d] = kss;
}

__global__ __launch_bounds__(512) void k_attn(
    const float* __restrict__ x, const float* __restrict__ qp,
    const float* __restrict__ ctxp, const float* __restrict__ ksump,
    const float* __restrict__ wo, const float* __restrict__ bo,
    const float* __restrict__ rot, const float* __restrict__ tqs,
    const float* __restrict__ w1, const float* __restrict__ b1,
    const float* __restrict__ w2, const float* __restrict__ b2,
    const float* __restrict__ g2,
    const float* __restrict__ gate_w, const float* __restrict__ gate_b,
    float* __restrict__ xmid, float* __restrict__ h2o,
    float* __restrict__ tw, int* __restrict__ cnt, int* __restrict__ list) {
  const int tid = threadIdx.x;
  const int o = tid & 127, ks = tid >> 7;
  const int n0 = blockIdx.x * 4;
  const int b = n0 >> 9;
  __shared__ float ctxs[NH * 256];
  __shared__ float kss[DM];
  __shared__ float rowA[4][DM], rowB[4][DM];
  __shared__ float red2[4][4][DM][2];
  __shared__ float redg[2][4][NE];
  __shared__ float lgl[4][NE];
  __shared__ float wredA[8], wredB[8];

  for (int idx = tid; idx < 2048; idx += 512) {
    float s = 0.0f;
#pragma unroll
    for (int tc = 0; tc < 8; ++tc) s += ctxp[tc * 8192 + b * 2048 + idx];
    ctxs[idx] = s;
  }
  if (tid < 128) {
    float s = 0.0f;
#pragma unroll
    for (int tc = 0; tc < 8; ++tc) s += ksump[tc * 512 + b * DM + tid];
    kss[tid] = s;
  }
  rowA[ks][o] = qp[(n0 + ks) * DM + o];
  __syncthreads();

  {
    int h = o >> 4, e = o & 15;
    float oa = 0.0f, qk = 0.0f;
#pragma unroll
    for (int d = 0; d < HD; ++d) {
      float qv = rowA[ks][h * HD + d];
      oa = fmaf(qv, ctxs[h * 256 + d * 16 + e], oa);
      qk = fmaf(qv, kss[h * HD + d], qk);
    }
    rowB[ks][o] = oa / (qk + 1e-6f);
  }
  __syncthreads();

  const int d0 = ks * 32;
  {
    float acc[4] = {0, 0, 0, 0};
    for (int dd = 0; dd < 32; ++dd) {
      int d = d0 + dd;
      float w = wo[d * DM + o];
#pragma unroll
      for (int g = 0; g < 4; ++g) acc[g] = fmaf(rowB[g][d], w, acc[g]);
    }
#pragma unroll
    for (int g = 0; g < 4; ++g) red2[ks][g][o][0] = acc[g];
  }
  __syncthreads();
  {
    float sa = bo[o];
#pragma unroll
    for (int s2 = 0; s2 < 4; ++s2) sa += red2[s2][ks][o][0];
    rowA[ks][o] = sa;
  }
  __syncthreads();

  {
    float acc[4] = {0, 0, 0, 0};
    for (int dd = 0; dd < 32; ++dd) {
      int d = d0 + dd;
      float r = rot[d * DM + o];
#pragma unroll
      for (int g = 0; g < 4; ++g) acc[g] = fmaf(rowA[g][d], r, acc[g]);
    }
#pragma unroll
    for (int g = 0; g < 4; ++g) red2[ks][g][o][1] = acc[g];
  }
  __syncthreads();
  {
    float y = 0.0f;
#pragma unroll
    for (int s2 = 0; s2 < 4; ++s2) y += red2[s2][ks][o][1];
    float ssq = wave_sum64(y * y);
    if ((tid & 63) == 0) wredA[tid >> 6] = ssq;
    __syncthreads();
    float tot = wredA[2 * ks] + wredA[2 * ks + 1];
    float mag = sqrtf(tot * (1.0f / 128.0f) + 1e-6f);
    float phase = y / mag;
    rowB[ks][o] = rintf(phase * 8.0f) * 0.125f * mag * tqs[o];
  }
  __syncthreads();

  {
    float a1[4] = {0, 0, 0, 0}, a2[4] = {0, 0, 0, 0};
    for (int dd = 0; dd < 32; ++dd) {
      int d = d0 + dd;
      float w1v = w1[d * DM + o];
      float w2v = w2[d * DM + o];
#pragma unroll
      for (int g = 0; g < 4; ++g) {
        float t = rowB[g][d];
        a1[g] = fmaf(t, w1v, a1[g]);
        a2[g] = fmaf(t, w2v, a2[g]);
      }
    }
#pragma unroll
    for (int g = 0; g < 4; ++g) {
      red2[ks][g][o][0] = a1[g];
      red2[ks][g][o][1] = a2[g];
    }
  }
  __syncthreads();
  {
    float ga = b1[o], up = b2[o];
#pragma unroll
    for (int s2 = 0; s2 < 4; ++s2) {
      ga += red2[s2][ks][o][0];
      up += red2[s2][ks][o][1];
    }
    float swv = ga * sigmoid_f(ga) * up;
    float xm = x[(n0 + ks) * DM + o] + swv;
    xmid[(n0 + ks) * DM + o] = xm;
    float ssq = wave_sum64(xm * xm);
    if ((tid & 63) == 0) wredB[tid >> 6] = ssq;
    __syncthreads();
    float tot = wredB[2 * ks] + wredB[2 * ks + 1];
    float rinv = 1.0f / sqrtf(tot * (1.0f / 128.0f) + 1e-6f);
    float h2v = g2[o] * xm * rinv;
    h2o[(n0 + ks) * DM + o] = h2v;
    rowA[ks][o] = h2v;
  }
  __syncthreads();

  {
    int e = tid & 255, kq = tid >> 8;
    float lg[4] = {0, 0, 0, 0};
    for (int dd = 0; dd < 64; ++dd) {
      int d = kq * 64 + dd;
      float gwv = gate_w[d * NE + e];
#pragma unroll
      for (int g = 0; g < 4; ++g) lg[g] = fmaf(rowA[g][d], gwv, lg[g]);
    }
#pragma unroll
    for (int g = 0; g < 4; ++g) redg[kq][g][e] = lg[g];
  }
  __syncthreads();
  {
    int e = tid & 255, half = tid >> 8;
    float gbv = gate_b[e];
#pragma unroll
    for (int gg2 = 0; gg2 < 2; ++gg2) {
      int g = half * 2 + gg2;
      lgl[g][e] = redg[0][g][e] + redg[1][g][e] + gbv;
    }
  }
  __syncthreads();

  if (tid < 256) {
    int lane = tid & 63, g = tid >> 6;
    float bv = -INFINITY;
    int bi = 0;
#pragma unroll
    for (int j2 = 0; j2 < 4; ++j2) {
      int e = lane + 64 * j2;
      float vv = lgl[g][e];
      if (vv > bv || (vv == bv && e < bi)) { bv = vv; bi = e; }
    }
#pragma unroll
    for (int m = 32; m; m >>= 1) {
      float pv = __shfl_xor(bv, m, 64);
      int pi = __shfl_xor(bi, m, 64);
      if (pv > bv || (pv == bv && pi < bi)) { bv = pv; bi = pi; }
    }
    float se = 0.0f;
#pragma unroll
    for (int j2 = 0; j2 < 4; ++j2) se += expf(lgl[g][lane + 64 * j2] - bv);
    se = wave_sum64(se);
    float mv = -INFINITY;
    int mi = 0;
#pragma unroll
    for (int j2 = 0; j2 < 4; ++j2) {
      int e = lane + 64 * j2;
      if (e != bi) {
        float vv = lgl[g][e];
        if (vv > mv || (vv == mv && e < mi)) { mv = vv; mi = e; }
      }
    }
#pragma unroll
    for (int m = 32; m; m >>= 1) {
      float pv = __shfl_xor(mv, m, 64);
      int pi = __shfl_xor(mi, m, 64);
      if (pv > mv || (pv == mv && pi < mi)) { mv = pv; mi = pi; }
    }
    if (lane == 0) {
      float v0 = 1.0f / se;
      float v1 = expf(mv - bv) / se;
      float wsum = v0 + v1 + 1e-6f;
      int t = n0 + g;
      tw[t * 2 + 0] = v0 / wsum;
      tw[t * 2 + 1] = v1 / wsum;
      int r0 = atomicAdd(&cnt[bi], 1);
      list[bi * CAP + r0] = t * 2 + 0;
      int r1 = atomicAdd(&cnt[mi], 1);
      list[mi * CAP + r1] = t * 2 + 1;
    }
  }
}

__global__ __launch_bounds__(512) void k_exp(
    const float* __restrict__ h2, const float* __restrict__ exp_w,
    const int* __restrict__ cnt, const int* __restrict__ list,
    float* __restrict__ elbuf) {
  const int e = blockIdx.x >> 1, half = blockIdx.x & 1;
  const int nt = cnt[e];
  if (half * 8 >= nt) return;
  const int tid = threadIdx.x;
  const int o = tid & 127, qq = tid >> 7;
  const float* W = exp_w + (size_t)e * (DM * DM);
  float wreg[32];
#pragma unroll
  for (int dd = 0; dd < 32; ++dd) wreg[dd] = W[(qq * 32 + dd) * DM + o];
  __shared__ float h2t[8][DM];
  __shared__ float psum[4][8][DM];
  __shared__ int alst[8];

  for (int i0 = half * 8; i0 < nt; i0 += 16) {
    int gn = min(8, nt - i0);
    for (int idx = tid; idx < gn * 128; idx += 512) {
      int j = idx >> 7;
      int a = list[e * CAP + i0 + j];
      h2t[j][idx & 127] = h2[(size_t)(a >> 1) * DM + (idx & 127)];
    }
    if (tid < gn) alst[tid] = list[e * CAP + i0 + tid];
    __syncthreads();
    for (int j = 0; j < gn; ++j) {
      const float4* hp = (const float4*)&h2t[j][qq * 32];
      float acc = 0.0f;
#pragma unroll
      for (int d4 = 0; d4 < 8; ++d4) {
        float4 hv = hp[d4];
        acc = fmaf(wreg[d4 * 4 + 0], hv.x, acc);
        acc = fmaf(wreg[d4 * 4 + 1], hv.y, acc);
        acc = fmaf(wreg[d4 * 4 + 2], hv.z, acc);
        acc = fmaf(wreg[d4 * 4 + 3], hv.w, acc);
      }
      psum[qq][j][o] = acc;
    }
    __syncthreads();
    for (int j = qq; j < gn; j += 4) {
      float r = psum[0][j][o] + psum[1][j][o] + psum[2][j][o] + psum[3][j][o];
      elbuf[(size_t)alst[j] * DM + o] = r;
    }
    __syncthreads();
  }
}

__global__ __launch_bounds__(1024) void k_comb(
    const float* __restrict__ elbuf, const float* __restrict__ tw,
    const float* __restrict__ xmid,
    const float* __restrict__ mw1, const float* __restrict__ mb1,
    const float* __restrict__ mw2, const float* __restrict__ mb2,
    float* __restrict__ out_x, float* __restrict__ out_cons) {
  const int tid = threadIdx.x;
  const int g = tid >> 7, o = tid & 127;
  const int t = blockIdx.x * 8 + g;
  __shared__ float was[8][DM];
  __shared__ float wredV[16];
  float w0 = tw[t * 2 + 0], w1 = tw[t * 2 + 1];
  float el0 = elbuf[(size_t)(t * 2 + 0) * DM + o];
  float el1 = elbuf[(size_t)(t * 2 + 1) * DM + o];
  was[g][o] = w0 * el0 + w1 * el1;
  __syncthreads();
  float a1 = mb1[o], a2 = mb2[o];
  for (int d = 0; d < DM; ++d) {
    float tt = was[g][d];
    a1 = fmaf(tt, mw1[d * DM + o], a1);
    a2 = fmaf(tt, mw2[d * DM + o], a2);
  }
  float swv = a1 * sigmoid_f(a1) * a2;
  out_x[(size_t)t * DM + o] = xmid[(size_t)t * DM + o] + swv;
  float dd0 = el0 - swv, dd1 = el1 - swv;
  float vt = wave_sum64(w0 * dd0 * dd0 + w1 * dd1 * dd1);
  if ((tid & 63) == 0) wredV[tid >> 6] = vt;
  __syncthreads();
  if (tid < 8)
    out_cons[blockIdx.x * 8 + tid] =
        expf(-(wredV[2 * tid] + wredV[2 * tid + 1]) * (1.0f / 128.0f));
}

extern "C" void kernel_launch(void* const* d_in, const int* in_sizes, int n_in,
                              void* d_out, int out_size, void* d_ws, size_t ws_size,
                              hipStream_t stream) {
  float* ws = (float*)d_ws;
  float* q = ws;                     // 262144
  float* kbuf = ws + 262144;         // 262144
  float* vbuf = ws + 524288;         // 262144
  float* ctxp = ws + 786432;         // 65536
  float* ksump = ws + 851968;        // 4096
  float* xmid = ws + 856064;         // 262144
  float* h2 = ws + 1118208;          // 262144
  float* tw = ws + 1380352;          // 4096
  float* elbuf = ws + 1384448;       // 524288
  int* cnt = (int*)(ws + 1908736);   // 256 ints
  int* list = (int*)(ws + 1908992);  // 256*4096 ints
  float* out_x = (float*)d_out;
  float* out_c = out_x + (size_t)NTOK * DM;

  MegaP hp;
  hp.x = (const float*)d_in[0];
  hp.g1 = (const float*)d_in[1];
  hp.wq = (const float*)d_in[2];
  hp.bq = (const float*)d_in[3];
  hp.wk = (const float*)d_in[4];
  hp.bk = (const float*)d_in[5];
  hp.wv = (const float*)d_in[6];
  hp.bv = (const float*)d_in[7];
  hp.wo = (const float*)d_in[8];
  hp.bo = (const float*)d_in[9];
  hp.rot = (const float*)d_in[10];
  hp.tqs = (const float*)d_in[11];
  hp.w1 = (const float*)d_in[12];
  hp.b1 = (const float*)d_in[13];
  hp.w2 = (const float*)d_in[14];
  hp.b2 = (const float*)d_in[15];
  hp.g2 = (const float*)d_in[16];
  hp.gw = (const float*)d_in[17];
  hp.gb = (const float*)d_in[18];
  hp.ew = (const float*)d_in[19];
  hp.mw1 = (const float*)d_in[20];
  hp.mb1 = (const float*)d_in[21];
  hp.mw2 = (const float*)d_in[22];
  hp.mb2 = (const float*)d_in[23];
  hp.q = q;
  hp.k = kbuf;
  hp.v = vbuf;
  hp.ctxp = ctxp;
  hp.ksump = ksump;
  hp.xmid = xmid;
  hp.h2 = h2;
  hp.tw = tw;
  hp.elbuf = elbuf;
  hp.cnt = cnt;
  hp.list = list;
  hp.out_x = out_x;
  hp.out_c = out_c;

  void* args[] = {&hp};
  hipError_t err =
      hipLaunchCooperativeKernel((const void*)mega, dim3(GRID), dim3(NTHR), args, 0, stream);
  if (err != hipSuccess) {
    // Fallback: round-7 five-kernel pipeline (verified, 64.7 us).
    hipLaunchKernelGGL(k_qkv, dim3(NTOK / 4), dim3(512), 0, stream,
                       hp.x, hp.g1, hp.wq, hp.bq, hp.wk, hp.bk, hp.wv, hp.bv,
                       q, kbuf, vbuf, cnt);
    hipLaunchKernelGGL(k_ctxp, dim3(256), dim3(256), 0, stream, kbuf, vbuf, ctxp, ksump);
    hipLaunchKernelGGL(k_attn, dim3(NTOK / 4), dim3(512), 0, stream,
                       hp.x, q, ctxp, ksump, hp.wo, hp.bo, hp.rot, hp.tqs,
                       hp.w1, hp.b1, hp.w2, hp.b2, hp.g2, hp.gw, hp.gb,
                       xmid, h2, tw, cnt, list);
    hipLaunchKernelGGL(k_exp, dim3(NE * 2), dim3(512), 0, stream, h2, hp.ew, cnt, list, elbuf);
    hipLaunchKernelGGL(k_comb, dim3(NTOK / 8), dim3(1024), 0, stream,
                       elbuf, tw, xmid, hp.mw1, hp.mb1, hp.mw2, hp.mb2, out_x, out_c);
  }
}

// Round 14
// 65.177 us; speedup vs baseline: 5.7297x; 5.7297x over previous
//
#include <hip/hip_runtime.h>
#include <math.h>

#define DM 128
#define SEQ 512
#define NTOK 2048
#define NH 8
#define HD 16
#define NE 256
#define CAP 4096

__device__ __forceinline__ float sigmoid_f(float v) { return 1.0f / (1.0f + expf(-v)); }

__device__ __forceinline__ float wave_sum64(float v) {
#pragma unroll
  for (int m = 32; m; m >>= 1) v += __shfl_xor(v, m, 64);
  return v;
}

// ---------------- Kernel A: rmsnorm + QKV + RoPE + elu+1 (+ cnt zeroing) ----------------
// 512 threads: o = tid&127 (output), ks = tid>>7 (k-slice / token)
__global__ __launch_bounds__(512) void k_qkv(
    const float* __restrict__ x, const float* __restrict__ g1,
    const float* __restrict__ wq, const float* __restrict__ bq,
    const float* __restrict__ wk, const float* __restrict__ bk,
    const float* __restrict__ wv, const float* __restrict__ bv_,
    float* __restrict__ q, float* __restrict__ k, float* __restrict__ v,
    int* __restrict__ cnt) {
  const int tid = threadIdx.x;
  const int o = tid & 127, ks = tid >> 7;
  const int n0 = blockIdx.x * 4;
  __shared__ float h1[4][DM];
  __shared__ float qr[4][DM], kr[4][DM];
  __shared__ float red3[4][4][DM][3];  // 24KB
  __shared__ float wredA[8];

  if (blockIdx.x == 0 && tid < NE) cnt[tid] = 0;

  float xv = x[(n0 + ks) * DM + o];
  float s = wave_sum64(xv * xv);
  if ((tid & 63) == 0) wredA[tid >> 6] = s;
  __syncthreads();
  float tot = wredA[2 * ks] + wredA[2 * ks + 1];
  float rinv = 1.0f / sqrtf(tot * (1.0f / 128.0f) + 1e-6f);
  h1[ks][o] = g1[o] * xv * rinv;
  __syncthreads();

  float aq[4] = {0, 0, 0, 0}, ak[4] = {0, 0, 0, 0}, av[4] = {0, 0, 0, 0};
  const int d0 = ks * 32;
  for (int dd = 0; dd < 32; ++dd) {
    int d = d0 + dd;
    float wqv = wq[d * DM + o], wkv = wk[d * DM + o], wvv = wv[d * DM + o];
#pragma unroll
    for (int g = 0; g < 4; ++g) {
      float hv = h1[g][d];
      aq[g] = fmaf(hv, wqv, aq[g]);
      ak[g] = fmaf(hv, wkv, ak[g]);
      av[g] = fmaf(hv, wvv, av[g]);
    }
  }
#pragma unroll
  for (int g = 0; g < 4; ++g) {
    red3[ks][g][o][0] = aq[g];
    red3[ks][g][o][1] = ak[g];
    red3[ks][g][o][2] = av[g];
  }
  __syncthreads();
  float sq = bq[o], sk = bk[o], sv = bv_[o];
#pragma unroll
  for (int s2 = 0; s2 < 4; ++s2) {
    sq += red3[s2][ks][o][0];
    sk += red3[s2][ks][o][1];
    sv += red3[s2][ks][o][2];
  }
  qr[ks][o] = sq;
  kr[ks][o] = sk;
  v[(n0 + ks) * DM + o] = sv;
  __syncthreads();

  const int i = o & 15, j = i & 7, hi = i & 8, lo = o & ~8;
  const float invf = expf(-(float)j * 1.1512925464970229f);  // ln(10000)/8
  int t = (n0 + ks) & (SEQ - 1);
  float ang = (float)t * invf;
  float sn = sinf(ang), cs = cosf(ang);
  float x1q = qr[ks][lo], x2q = qr[ks][lo + 8];
  float x1k = kr[ks][lo], x2k = kr[ks][lo + 8];
  float rq = hi ? (x1q * sn + x2q * cs) : (x1q * cs - x2q * sn);
  float rk = hi ? (x1k * sn + x2k * cs) : (x1k * cs - x2k * sn);
  rq = (rq > 0.0f) ? rq + 1.0f : expf(rq);
  rk = (rk > 0.0f) ? rk + 1.0f : expf(rk);
  q[(n0 + ks) * DM + o] = rq;
  k[(n0 + ks) * DM + o] = rk;
}

// ---------------- Kernel B: ctx/ksum partials, per (b,h,tchunk) ----------------
__global__ __launch_bounds__(256) void k_ctxp(
    const float* __restrict__ k, const float* __restrict__ v,
    float* __restrict__ ctxp, float* __restrict__ ksump) {
  const int bh = blockIdx.x & 31, tc = blockIdx.x >> 5;
  const int b = bh >> 3, h = bh & 7;
  const int p = threadIdx.x, d = p >> 4, e = p & 15;
  const float* kb = k + (size_t)b * SEQ * DM + h * HD;
  const float* vb = v + (size_t)b * SEQ * DM + h * HD;
  float acc = 0.0f, kss = 0.0f;
  for (int tt = 0; tt < 64; ++tt) {
    int t = tc * 64 + tt;
    float kv = kb[t * DM + d];
    float vv = vb[t * DM + e];
    acc = fmaf(kv, vv, acc);
    kss += kv;
  }
  ctxp[tc * 8192 + bh * 256 + p] = acc;
  if (e == 0) ksump[tc * 512 + bh * HD + d] = kss;
}

// ------- Kernel C: attn + wo + turbo_quant + swiglu + residual + rmsnorm + gate (512 thr, r7) -------
__global__ __launch_bounds__(512) void k_attn(
    const float* __restrict__ x, const float* __restrict__ qp,
    const float* __restrict__ ctxp, const float* __restrict__ ksump,
    const float* __restrict__ wo, const float* __restrict__ bo,
    const float* __restrict__ rot, const float* __restrict__ tqs,
    const float* __restrict__ w1, const float* __restrict__ b1,
    const float* __restrict__ w2, const float* __restrict__ b2,
    const float* __restrict__ g2,
    const float* __restrict__ gate_w, const float* __restrict__ gate_b,
    float* __restrict__ xmid, float* __restrict__ h2o,
    float* __restrict__ tw, int* __restrict__ cnt, int* __restrict__ list) {
  const int tid = threadIdx.x;
  const int o = tid & 127, ks = tid >> 7;
  const int n0 = blockIdx.x * 4;
  const int b = n0 >> 9;
  __shared__ float ctxs[NH * 256];
  __shared__ float kss[DM];
  __shared__ float rowA[4][DM], rowB[4][DM];
  __shared__ float red2[4][4][DM][2];
  __shared__ float redg[2][4][NE];
  __shared__ float lgl[4][NE];
  __shared__ float wredA[8], wredB[8];

  for (int idx = tid; idx < 2048; idx += 512) {
    float s = 0.0f;
#pragma unroll
    for (int tc = 0; tc < 8; ++tc) s += ctxp[tc * 8192 + b * 2048 + idx];
    ctxs[idx] = s;
  }
  if (tid < 128) {
    float s = 0.0f;
#pragma unroll
    for (int tc = 0; tc < 8; ++tc) s += ksump[tc * 512 + b * DM + tid];
    kss[tid] = s;
  }
  rowA[ks][o] = qp[(n0 + ks) * DM + o];
  __syncthreads();

  {
    int h = o >> 4, e = o & 15;
    float oa = 0.0f, qk = 0.0f;
#pragma unroll
    for (int d = 0; d < HD; ++d) {
      float qv = rowA[ks][h * HD + d];
      oa = fmaf(qv, ctxs[h * 256 + d * 16 + e], oa);
      qk = fmaf(qv, kss[h * HD + d], qk);
    }
    rowB[ks][o] = oa / (qk + 1e-6f);
  }
  __syncthreads();

  const int d0 = ks * 32;
  {
    float acc[4] = {0, 0, 0, 0};
    for (int dd = 0; dd < 32; ++dd) {
      int d = d0 + dd;
      float w = wo[d * DM + o];
#pragma unroll
      for (int g = 0; g < 4; ++g) acc[g] = fmaf(rowB[g][d], w, acc[g]);
    }
#pragma unroll
    for (int g = 0; g < 4; ++g) red2[ks][g][o][0] = acc[g];
  }
  __syncthreads();
  {
    float sa = bo[o];
#pragma unroll
    for (int s2 = 0; s2 < 4; ++s2) sa += red2[s2][ks][o][0];
    rowA[ks][o] = sa;
  }
  __syncthreads();

  {
    float acc[4] = {0, 0, 0, 0};
    for (int dd = 0; dd < 32; ++dd) {
      int d = d0 + dd;
      float r = rot[d * DM + o];
#pragma unroll
      for (int g = 0; g < 4; ++g) acc[g] = fmaf(rowA[g][d], r, acc[g]);
    }
#pragma unroll
    for (int g = 0; g < 4; ++g) red2[ks][g][o][1] = acc[g];
  }
  __syncthreads();
  {
    float y = 0.0f;
#pragma unroll
    for (int s2 = 0; s2 < 4; ++s2) y += red2[s2][ks][o][1];
    float ssq = wave_sum64(y * y);
    if ((tid & 63) == 0) wredA[tid >> 6] = ssq;
    __syncthreads();
    float tot = wredA[2 * ks] + wredA[2 * ks + 1];
    float mag = sqrtf(tot * (1.0f / 128.0f) + 1e-6f);
    float phase = y / mag;
    rowB[ks][o] = rintf(phase * 8.0f) * 0.125f * mag * tqs[o];
  }
  __syncthreads();

  {
    float a1[4] = {0, 0, 0, 0}, a2[4] = {0, 0, 0, 0};
    for (int dd = 0; dd < 32; ++dd) {
      int d = d0 + dd;
      float w1v = w1[d * DM + o];
      float w2v = w2[d * DM + o];
#pragma unroll
      for (int g = 0; g < 4; ++g) {
        float t = rowB[g][d];
        a1[g] = fmaf(t, w1v, a1[g]);
        a2[g] = fmaf(t, w2v, a2[g]);
      }
    }
#pragma unroll
    for (int g = 0; g < 4; ++g) {
      red2[ks][g][o][0] = a1[g];
      red2[ks][g][o][1] = a2[g];
    }
  }
  __syncthreads();
  {
    float ga = b1[o], up = b2[o];
#pragma unroll
    for (int s2 = 0; s2 < 4; ++s2) {
      ga += red2[s2][ks][o][0];
      up += red2[s2][ks][o][1];
    }
    float swv = ga * sigmoid_f(ga) * up;
    float xm = x[(n0 + ks) * DM + o] + swv;
    xmid[(n0 + ks) * DM + o] = xm;
    float ssq = wave_sum64(xm * xm);
    if ((tid & 63) == 0) wredB[tid >> 6] = ssq;
    __syncthreads();
    float tot = wredB[2 * ks] + wredB[2 * ks + 1];
    float rinv = 1.0f / sqrtf(tot * (1.0f / 128.0f) + 1e-6f);
    float h2v = g2[o] * xm * rinv;
    h2o[(n0 + ks) * DM + o] = h2v;
    rowA[ks][o] = h2v;
  }
  __syncthreads();

  {
    int e = tid & 255, kq = tid >> 8;
    float lg[4] = {0, 0, 0, 0};
    for (int dd = 0; dd < 64; ++dd) {
      int d = kq * 64 + dd;
      float gwv = gate_w[d * NE + e];
#pragma unroll
      for (int g = 0; g < 4; ++g) lg[g] = fmaf(rowA[g][d], gwv, lg[g]);
    }
#pragma unroll
    for (int g = 0; g < 4; ++g) redg[kq][g][e] = lg[g];
  }
  __syncthreads();
  {
    int e = tid & 255, half = tid >> 8;
    float gbv = gate_b[e];
#pragma unroll
    for (int gg2 = 0; gg2 < 2; ++gg2) {
      int g = half * 2 + gg2;
      lgl[g][e] = redg[0][g][e] + redg[1][g][e] + gbv;
    }
  }
  __syncthreads();

  if (tid < 256) {
    int lane = tid & 63, g = tid >> 6;
    float bv = -INFINITY;
    int bi = 0;
#pragma unroll
    for (int j2 = 0; j2 < 4; ++j2) {
      int e = lane + 64 * j2;
      float vv = lgl[g][e];
      if (vv > bv || (vv == bv && e < bi)) { bv = vv; bi = e; }
    }
#pragma unroll
    for (int m = 32; m; m >>= 1) {
      float pv = __shfl_xor(bv, m, 64);
      int pi = __shfl_xor(bi, m, 64);
      if (pv > bv || (pv == bv && pi < bi)) { bv = pv; bi = pi; }
    }
    float se = 0.0f;
#pragma unroll
    for (int j2 = 0; j2 < 4; ++j2) se += expf(lgl[g][lane + 64 * j2] - bv);
    se = wave_sum64(se);
    float mv = -INFINITY;
    int mi = 0;
#pragma unroll
    for (int j2 = 0; j2 < 4; ++j2) {
      int e = lane + 64 * j2;
      if (e != bi) {
        float vv = lgl[g][e];
        if (vv > mv || (vv == mv && e < mi)) { mv = vv; mi = e; }
      }
    }
#pragma unroll
    for (int m = 32; m; m >>= 1) {
      float pv = __shfl_xor(mv, m, 64);
      int pi = __shfl_xor(mi, m, 64);
      if (pv > mv || (pv == mv && pi < mi)) { mv = pv; mi = pi; }
    }
    if (lane == 0) {
      float v0 = 1.0f / se;
      float v1 = expf(mv - bv) / se;
      float wsum = v0 + v1 + 1e-6f;
      int t = n0 + g;
      tw[t * 2 + 0] = v0 / wsum;
      tw[t * 2 + 1] = v1 / wsum;
      int r0 = atomicAdd(&cnt[bi], 1);
      list[bi * CAP + r0] = t * 2 + 0;
      int r1 = atomicAdd(&cnt[mi], 1);
      list[mi * CAP + r1] = t * 2 + 1;
    }
  }
}

// ---------------- Kernel D: expert-centric GEMVs (4 blocks per expert) ----------------
// 1024 blocks: expert = bid>>2, quarter = bid&3 takes interleaved 8-token batches.
__global__ __launch_bounds__(512) void k_exp(
    const float* __restrict__ h2, const float* __restrict__ exp_w,
    const int* __restrict__ cnt, const int* __restrict__ list,
    float* __restrict__ elbuf) {
  const int e = blockIdx.x >> 2, quarter = blockIdx.x & 3;
  const int nt = cnt[e];
  if (quarter * 8 >= nt) return;
  const int tid = threadIdx.x;
  const int o = tid & 127, qq = tid >> 7;
  const float* W = exp_w + (size_t)e * (DM * DM);
  float wreg[32];
#pragma unroll
  for (int dd = 0; dd < 32; ++dd) wreg[dd] = W[(qq * 32 + dd) * DM + o];
  __shared__ float h2t[8][DM];
  __shared__ float psum[4][8][DM];
  __shared__ int alst[8];

  for (int i0 = quarter * 8; i0 < nt; i0 += 32) {
    int gn = min(8, nt - i0);
    for (int idx = tid; idx < gn * 128; idx += 512) {
      int j = idx >> 7;
      int a = list[e * CAP + i0 + j];
      h2t[j][idx & 127] = h2[(size_t)(a >> 1) * DM + (idx & 127)];
    }
    if (tid < gn) alst[tid] = list[e * CAP + i0 + tid];
    __syncthreads();
    for (int j = 0; j < gn; ++j) {
      const float4* hp = (const float4*)&h2t[j][qq * 32];
      float acc = 0.0f;
#pragma unroll
      for (int d4 = 0; d4 < 8; ++d4) {
        float4 hv = hp[d4];
        acc = fmaf(wreg[d4 * 4 + 0], hv.x, acc);
        acc = fmaf(wreg[d4 * 4 + 1], hv.y, acc);
        acc = fmaf(wreg[d4 * 4 + 2], hv.z, acc);
        acc = fmaf(wreg[d4 * 4 + 3], hv.w, acc);
      }
      psum[qq][j][o] = acc;
    }
    __syncthreads();
    for (int j = qq; j < gn; j += 4) {
      float r = psum[0][j][o] + psum[1][j][o] + psum[2][j][o] + psum[3][j][o];
      elbuf[(size_t)alst[j] * DM + o] = r;
    }
    __syncthreads();
  }
}

// ---------------- Kernel E: combine + swiglu + residual + consensus ----------------
// 256 blocks x 1024 threads, 8 tokens/block, plain 128-FMA chains
__global__ __launch_bounds__(1024) void k_comb(
    const float* __restrict__ elbuf, const float* __restrict__ tw,
    const float* __restrict__ xmid,
    const float* __restrict__ mw1, const float* __restrict__ mb1,
    const float* __restrict__ mw2, const float* __restrict__ mb2,
    float* __restrict__ out_x, float* __restrict__ out_cons) {
  const int tid = threadIdx.x;
  const int g = tid >> 7, o = tid & 127;
  const int t = blockIdx.x * 8 + g;
  __shared__ float was[8][DM];
  __shared__ float wredV[16];
  float w0 = tw[t * 2 + 0], w1 = tw[t * 2 + 1];
  float el0 = elbuf[(size_t)(t * 2 + 0) * DM + o];
  float el1 = elbuf[(size_t)(t * 2 + 1) * DM + o];
  was[g][o] = w0 * el0 + w1 * el1;
  __syncthreads();
  float a1 = mb1[o], a2 = mb2[o];
  for (int d = 0; d < DM; ++d) {
    float tt = was[g][d];
    a1 = fmaf(tt, mw1[d * DM + o], a1);
    a2 = fmaf(tt, mw2[d * DM + o], a2);
  }
  float swv = a1 * sigmoid_f(a1) * a2;
  out_x[(size_t)t * DM + o] = xmid[(size_t)t * DM + o] + swv;
  float dd0 = el0 - swv, dd1 = el1 - swv;
  float vt = wave_sum64(w0 * dd0 * dd0 + w1 * dd1 * dd1);
  if ((tid & 63) == 0) wredV[tid >> 6] = vt;
  __syncthreads();
  if (tid < 8)
    out_cons[blockIdx.x * 8 + tid] =
        expf(-(wredV[2 * tid] + wredV[2 * tid + 1]) * (1.0f / 128.0f));
}

extern "C" void kernel_launch(void* const* d_in, const int* in_sizes, int n_in,
                              void* d_out, int out_size, void* d_ws, size_t ws_size,
                              hipStream_t stream) {
  const float* x = (const float*)d_in[0];
  const float* g1 = (const float*)d_in[1];
  const float* wq = (const float*)d_in[2];
  const float* bq = (const float*)d_in[3];
  const float* wk = (const float*)d_in[4];
  const float* bk = (const float*)d_in[5];
  const float* wv = (const float*)d_in[6];
  const float* bv = (const float*)d_in[7];
  const float* wo = (const float*)d_in[8];
  const float* bo = (const float*)d_in[9];
  const float* rot = (const float*)d_in[10];
  const float* tqs = (const float*)d_in[11];
  const float* sw1 = (const float*)d_in[12];
  const float* sb1 = (const float*)d_in[13];
  const float* sw2 = (const float*)d_in[14];
  const float* sb2 = (const float*)d_in[15];
  const float* g2 = (const float*)d_in[16];
  const float* gw = (const float*)d_in[17];
  const float* gb = (const float*)d_in[18];
  const float* ew = (const float*)d_in[19];
  const float* mw1 = (const float*)d_in[20];
  const float* mb1 = (const float*)d_in[21];
  const float* mw2 = (const float*)d_in[22];
  const float* mb2 = (const float*)d_in[23];

  float* ws = (float*)d_ws;
  float* q = ws;                     // 262144
  float* kbuf = ws + 262144;         // 262144
  float* vbuf = ws + 524288;         // 262144
  float* ctxp = ws + 786432;         // 65536
  float* ksump = ws + 851968;        // 4096
  float* xmid = ws + 856064;         // 262144
  float* h2 = ws + 1118208;          // 262144
  float* tw = ws + 1380352;          // 4096
  float* elbuf = ws + 1384448;       // 524288
  int* cnt = (int*)(ws + 1908736);   // 256 ints
  int* list = (int*)(ws + 1908992);  // 256*4096 ints
  float* out_x = (float*)d_out;
  float* out_c = out_x + (size_t)NTOK * DM;

  hipLaunchKernelGGL(k_qkv, dim3(NTOK / 4), dim3(512), 0, stream,
                     x, g1, wq, bq, wk, bk, wv, bv, q, kbuf, vbuf, cnt);
  hipLaunchKernelGGL(k_ctxp, dim3(256), dim3(256), 0, stream, kbuf, vbuf, ctxp, ksump);
  hipLaunchKernelGGL(k_attn, dim3(NTOK / 4), dim3(512), 0, stream,
                     x, q, ctxp, ksump, wo, bo, rot, tqs, sw1, sb1, sw2, sb2, g2,
                     gw, gb, xmid, h2, tw, cnt, list);
  hipLaunchKernelGGL(k_exp, dim3(NE * 4), dim3(512), 0, stream, h2, ew, cnt, list, elbuf);
  hipLaunchKernelGGL(k_comb, dim3(NTOK / 8), dim3(1024), 0, stream,
                     elbuf, tw, xmid, mw1, mb1, mw2, mb2, out_x, out_c);
}

// Round 15
// 64.610 us; speedup vs baseline: 5.7800x; 1.0088x over previous
//
#include <hip/hip_runtime.h>
#include <math.h>

#define DM 128
#define SEQ 512
#define NTOK 2048
#define NH 8
#define HD 16
#define NE 256
#define CAP 4096

__device__ __forceinline__ float sigmoid_f(float v) { return 1.0f / (1.0f + expf(-v)); }

__device__ __forceinline__ float wave_sum64(float v) {
#pragma unroll
  for (int m = 32; m; m >>= 1) v += __shfl_xor(v, m, 64);
  return v;
}

// ---------------- Kernel A: rmsnorm + QKV + RoPE + elu+1 (+ cnt zeroing) ----------------
// 512 threads: o = tid&127 (output), ks = tid>>7 (k-slice / token)
__global__ __launch_bounds__(512) void k_qkv(
    const float* __restrict__ x, const float* __restrict__ g1,
    const float* __restrict__ wq, const float* __restrict__ bq,
    const float* __restrict__ wk, const float* __restrict__ bk,
    const float* __restrict__ wv, const float* __restrict__ bv_,
    float* __restrict__ q, float* __restrict__ k, float* __restrict__ v,
    int* __restrict__ cnt) {
  const int tid = threadIdx.x;
  const int o = tid & 127, ks = tid >> 7;
  const int n0 = blockIdx.x * 4;
  __shared__ float h1[4][DM];
  __shared__ float qr[4][DM], kr[4][DM];
  __shared__ float red3[4][4][DM][3];  // 24KB
  __shared__ float wredA[8];

  if (blockIdx.x == 0 && tid < NE) cnt[tid] = 0;

  float xv = x[(n0 + ks) * DM + o];
  float s = wave_sum64(xv * xv);
  if ((tid & 63) == 0) wredA[tid >> 6] = s;
  __syncthreads();
  float tot = wredA[2 * ks] + wredA[2 * ks + 1];
  float rinv = 1.0f / sqrtf(tot * (1.0f / 128.0f) + 1e-6f);
  h1[ks][o] = g1[o] * xv * rinv;
  __syncthreads();

  float aq[4] = {0, 0, 0, 0}, ak[4] = {0, 0, 0, 0}, av[4] = {0, 0, 0, 0};
  const int d0 = ks * 32;
  for (int dd = 0; dd < 32; ++dd) {
    int d = d0 + dd;
    float wqv = wq[d * DM + o], wkv = wk[d * DM + o], wvv = wv[d * DM + o];
#pragma unroll
    for (int g = 0; g < 4; ++g) {
      float hv = h1[g][d];
      aq[g] = fmaf(hv, wqv, aq[g]);
      ak[g] = fmaf(hv, wkv, ak[g]);
      av[g] = fmaf(hv, wvv, av[g]);
    }
  }
#pragma unroll
  for (int g = 0; g < 4; ++g) {
    red3[ks][g][o][0] = aq[g];
    red3[ks][g][o][1] = ak[g];
    red3[ks][g][o][2] = av[g];
  }
  __syncthreads();
  float sq = bq[o], sk = bk[o], sv = bv_[o];
#pragma unroll
  for (int s2 = 0; s2 < 4; ++s2) {
    sq += red3[s2][ks][o][0];
    sk += red3[s2][ks][o][1];
    sv += red3[s2][ks][o][2];
  }
  qr[ks][o] = sq;
  kr[ks][o] = sk;
  v[(n0 + ks) * DM + o] = sv;
  __syncthreads();

  const int i = o & 15, j = i & 7, hi = i & 8, lo = o & ~8;
  const float invf = expf(-(float)j * 1.1512925464970229f);  // ln(10000)/8
  int t = (n0 + ks) & (SEQ - 1);
  float ang = (float)t * invf;
  float sn = sinf(ang), cs = cosf(ang);
  float x1q = qr[ks][lo], x2q = qr[ks][lo + 8];
  float x1k = kr[ks][lo], x2k = kr[ks][lo + 8];
  float rq = hi ? (x1q * sn + x2q * cs) : (x1q * cs - x2q * sn);
  float rk = hi ? (x1k * sn + x2k * cs) : (x1k * cs - x2k * sn);
  rq = (rq > 0.0f) ? rq + 1.0f : expf(rq);
  rk = (rk > 0.0f) ? rk + 1.0f : expf(rk);
  q[(n0 + ks) * DM + o] = rq;
  k[(n0 + ks) * DM + o] = rk;
}

// ---------------- Kernel B: ctx/ksum partials, per (b,h,tchunk) ----------------
__global__ __launch_bounds__(256) void k_ctxp(
    const float* __restrict__ k, const float* __restrict__ v,
    float* __restrict__ ctxp, float* __restrict__ ksump) {
  const int bh = blockIdx.x & 31, tc = blockIdx.x >> 5;
  const int b = bh >> 3, h = bh & 7;
  const int p = threadIdx.x, d = p >> 4, e = p & 15;
  const float* kb = k + (size_t)b * SEQ * DM + h * HD;
  const float* vb = v + (size_t)b * SEQ * DM + h * HD;
  float acc = 0.0f, kss = 0.0f;
  for (int tt = 0; tt < 64; ++tt) {
    int t = tc * 64 + tt;
    float kv = kb[t * DM + d];
    float vv = vb[t * DM + e];
    acc = fmaf(kv, vv, acc);
    kss += kv;
  }
  ctxp[tc * 8192 + bh * 256 + p] = acc;
  if (e == 0) ksump[tc * 512 + bh * HD + d] = kss;
}

// ------- Kernel C: attn + wo + turbo_quant + swiglu + residual + rmsnorm + gate (fused) -------
// 512 threads: o = tid&127, ks = tid>>7
__global__ __launch_bounds__(512) void k_attn(
    const float* __restrict__ x, const float* __restrict__ qp,
    const float* __restrict__ ctxp, const float* __restrict__ ksump,
    const float* __restrict__ wo, const float* __restrict__ bo,
    const float* __restrict__ rot, const float* __restrict__ tqs,
    const float* __restrict__ w1, const float* __restrict__ b1,
    const float* __restrict__ w2, const float* __restrict__ b2,
    const float* __restrict__ g2,
    const float* __restrict__ gate_w, const float* __restrict__ gate_b,
    float* __restrict__ xmid, float* __restrict__ h2o,
    float* __restrict__ tw, int* __restrict__ cnt, int* __restrict__ list) {
  const int tid = threadIdx.x;
  const int o = tid & 127, ks = tid >> 7;
  const int n0 = blockIdx.x * 4;
  const int b = n0 >> 9;
  __shared__ float ctxs[NH * 256];  // 8KB
  __shared__ float kss[DM];
  __shared__ float rowA[4][DM], rowB[4][DM];
  __shared__ float red2[4][4][DM][2];  // 16KB
  __shared__ float redg[2][4][NE];     // 8KB
  __shared__ float lgl[4][NE];         // 4KB
  __shared__ float wredA[8], wredB[8];

  for (int idx = tid; idx < 2048; idx += 512) {
    float s = 0.0f;
#pragma unroll
    for (int tc = 0; tc < 8; ++tc) s += ctxp[tc * 8192 + b * 2048 + idx];
    ctxs[idx] = s;
  }
  if (tid < 128) {
    float s = 0.0f;
#pragma unroll
    for (int tc = 0; tc < 8; ++tc) s += ksump[tc * 512 + b * DM + tid];
    kss[tid] = s;
  }
  rowA[ks][o] = qp[(n0 + ks) * DM + o];
  __syncthreads();

  {
    int h = o >> 4, e = o & 15;
    float oa = 0.0f, qk = 0.0f;
#pragma unroll
    for (int d = 0; d < HD; ++d) {
      float qv = rowA[ks][h * HD + d];
      oa = fmaf(qv, ctxs[h * 256 + d * 16 + e], oa);
      qk = fmaf(qv, kss[h * HD + d], qk);
    }
    rowB[ks][o] = oa / (qk + 1e-6f);
  }
  __syncthreads();

  const int d0 = ks * 32;
  {
    float acc[4] = {0, 0, 0, 0};
    for (int dd = 0; dd < 32; ++dd) {
      int d = d0 + dd;
      float w = wo[d * DM + o];
#pragma unroll
      for (int g = 0; g < 4; ++g) acc[g] = fmaf(rowB[g][d], w, acc[g]);
    }
#pragma unroll
    for (int g = 0; g < 4; ++g) red2[ks][g][o][0] = acc[g];
  }
  __syncthreads();
  {
    float sa = bo[o];
#pragma unroll
    for (int s2 = 0; s2 < 4; ++s2) sa += red2[s2][ks][o][0];
    rowA[ks][o] = sa;
  }
  __syncthreads();

  {
    float acc[4] = {0, 0, 0, 0};
    for (int dd = 0; dd < 32; ++dd) {
      int d = d0 + dd;
      float r = rot[d * DM + o];
#pragma unroll
      for (int g = 0; g < 4; ++g) acc[g] = fmaf(rowA[g][d], r, acc[g]);
    }
#pragma unroll
    for (int g = 0; g < 4; ++g) red2[ks][g][o][1] = acc[g];
  }
  __syncthreads();
  {
    float y = 0.0f;
#pragma unroll
    for (int s2 = 0; s2 < 4; ++s2) y += red2[s2][ks][o][1];
    float ssq = wave_sum64(y * y);
    if ((tid & 63) == 0) wredA[tid >> 6] = ssq;
    __syncthreads();
    float tot = wredA[2 * ks] + wredA[2 * ks + 1];
    float mag = sqrtf(tot * (1.0f / 128.0f) + 1e-6f);
    float phase = y / mag;
    rowB[ks][o] = rintf(phase * 8.0f) * 0.125f * mag * tqs[o];
  }
  __syncthreads();

  {
    float a1[4] = {0, 0, 0, 0}, a2[4] = {0, 0, 0, 0};
    for (int dd = 0; dd < 32; ++dd) {
      int d = d0 + dd;
      float w1v = w1[d * DM + o];
      float w2v = w2[d * DM + o];
#pragma unroll
      for (int g = 0; g < 4; ++g) {
        float t = rowB[g][d];
        a1[g] = fmaf(t, w1v, a1[g]);
        a2[g] = fmaf(t, w2v, a2[g]);
      }
    }
#pragma unroll
    for (int g = 0; g < 4; ++g) {
      red2[ks][g][o][0] = a1[g];
      red2[ks][g][o][1] = a2[g];
    }
  }
  __syncthreads();
  {
    float ga = b1[o], up = b2[o];
#pragma unroll
    for (int s2 = 0; s2 < 4; ++s2) {
      ga += red2[s2][ks][o][0];
      up += red2[s2][ks][o][1];
    }
    float swv = ga * sigmoid_f(ga) * up;
    float xm = x[(n0 + ks) * DM + o] + swv;
    xmid[(n0 + ks) * DM + o] = xm;
    float ssq = wave_sum64(xm * xm);
    if ((tid & 63) == 0) wredB[tid >> 6] = ssq;
    __syncthreads();
    float tot = wredB[2 * ks] + wredB[2 * ks + 1];
    float rinv = 1.0f / sqrtf(tot * (1.0f / 128.0f) + 1e-6f);
    float h2v = g2[o] * xm * rinv;
    h2o[(n0 + ks) * DM + o] = h2v;
    rowA[ks][o] = h2v;
  }
  __syncthreads();

  {
    int e = tid & 255, kq = tid >> 8;
    float lg[4] = {0, 0, 0, 0};
    for (int dd = 0; dd < 64; ++dd) {
      int d = kq * 64 + dd;
      float gwv = gate_w[d * NE + e];
#pragma unroll
      for (int g = 0; g < 4; ++g) lg[g] = fmaf(rowA[g][d], gwv, lg[g]);
    }
#pragma unroll
    for (int g = 0; g < 4; ++g) redg[kq][g][e] = lg[g];
  }
  __syncthreads();
  {
    int e = tid & 255, half = tid >> 8;
    float gbv = gate_b[e];
#pragma unroll
    for (int gg2 = 0; gg2 < 2; ++gg2) {
      int g = half * 2 + gg2;
      lgl[g][e] = redg[0][g][e] + redg[1][g][e] + gbv;
    }
  }
  __syncthreads();

  if (tid < 256) {
    int lane = tid & 63, g = tid >> 6;
    float bv = -INFINITY;
    int bi = 0;
#pragma unroll
    for (int j2 = 0; j2 < 4; ++j2) {
      int e = lane + 64 * j2;
      float vv = lgl[g][e];
      if (vv > bv || (vv == bv && e < bi)) { bv = vv; bi = e; }
    }
#pragma unroll
    for (int m = 32; m; m >>= 1) {
      float pv = __shfl_xor(bv, m, 64);
      int pi = __shfl_xor(bi, m, 64);
      if (pv > bv || (pv == bv && pi < bi)) { bv = pv; bi = pi; }
    }
    float se = 0.0f;
#pragma unroll
    for (int j2 = 0; j2 < 4; ++j2) se += expf(lgl[g][lane + 64 * j2] - bv);
    se = wave_sum64(se);
    float mv = -INFINITY;
    int mi = 0;
#pragma unroll
    for (int j2 = 0; j2 < 4; ++j2) {
      int e = lane + 64 * j2;
      if (e != bi) {
        float vv = lgl[g][e];
        if (vv > mv || (vv == mv && e < mi)) { mv = vv; mi = e; }
      }
    }
#pragma unroll
    for (int m = 32; m; m >>= 1) {
      float pv = __shfl_xor(mv, m, 64);
      int pi = __shfl_xor(mi, m, 64);
      if (pv > mv || (pv == mv && pi < mi)) { mv = pv; mi = pi; }
    }
    if (lane == 0) {
      float v0 = 1.0f / se;
      float v1 = expf(mv - bv) / se;
      float wsum = v0 + v1 + 1e-6f;
      int t = n0 + g;
      tw[t * 2 + 0] = v0 / wsum;
      tw[t * 2 + 1] = v1 / wsum;
      int r0 = atomicAdd(&cnt[bi], 1);
      list[bi * CAP + r0] = t * 2 + 0;
      int r1 = atomicAdd(&cnt[mi], 1);
      list[mi * CAP + r1] = t * 2 + 1;
    }
  }
}

// ---------------- Kernel D: expert-centric GEMVs (2 blocks per expert) ----------------
__global__ __launch_bounds__(512) void k_exp(
    const float* __restrict__ h2, const float* __restrict__ exp_w,
    const int* __restrict__ cnt, const int* __restrict__ list,
    float* __restrict__ elbuf) {
  const int e = blockIdx.x >> 1, half = blockIdx.x & 1;
  const int nt = cnt[e];
  if (half * 8 >= nt) return;
  const int tid = threadIdx.x;
  const int o = tid & 127, qq = tid >> 7;
  const float* W = exp_w + (size_t)e * (DM * DM);
  float wreg[32];
#pragma unroll
  for (int dd = 0; dd < 32; ++dd) wreg[dd] = W[(qq * 32 + dd) * DM + o];
  __shared__ float h2t[8][DM];
  __shared__ float psum[4][8][DM];
  __shared__ int alst[8];

  for (int i0 = half * 8; i0 < nt; i0 += 16) {
    int gn = min(8, nt - i0);
    for (int idx = tid; idx < gn * 128; idx += 512) {
      int j = idx >> 7;
      int a = list[e * CAP + i0 + j];
      h2t[j][idx & 127] = h2[(size_t)(a >> 1) * DM + (idx & 127)];
    }
    if (tid < gn) alst[tid] = list[e * CAP + i0 + tid];
    __syncthreads();
    for (int j = 0; j < gn; ++j) {
      const float4* hp = (const float4*)&h2t[j][qq * 32];
      float acc = 0.0f;
#pragma unroll
      for (int d4 = 0; d4 < 8; ++d4) {
        float4 hv = hp[d4];
        acc = fmaf(wreg[d4 * 4 + 0], hv.x, acc);
        acc = fmaf(wreg[d4 * 4 + 1], hv.y, acc);
        acc = fmaf(wreg[d4 * 4 + 2], hv.z, acc);
        acc = fmaf(wreg[d4 * 4 + 3], hv.w, acc);
      }
      psum[qq][j][o] = acc;
    }
    __syncthreads();
    for (int j = qq; j < gn; j += 4) {
      float r = psum[0][j][o] + psum[1][j][o] + psum[2][j][o] + psum[3][j][o];
      elbuf[(size_t)alst[j] * DM + o] = r;
    }
    __syncthreads();
  }
}

// ---------------- Kernel E: combine + swiglu + residual + consensus ----------------
// 256 blocks x 1024 threads, 8 tokens/block, plain 128-FMA chains
__global__ __launch_bounds__(1024) void k_comb(
    const float* __restrict__ elbuf, const float* __restrict__ tw,
    const float* __restrict__ xmid,
    const float* __restrict__ mw1, const float* __restrict__ mb1,
    const float* __restrict__ mw2, const float* __restrict__ mb2,
    float* __restrict__ out_x, float* __restrict__ out_cons) {
  const int tid = threadIdx.x;
  const int g = tid >> 7, o = tid & 127;
  const int t = blockIdx.x * 8 + g;
  __shared__ float was[8][DM];
  __shared__ float wredV[16];
  float w0 = tw[t * 2 + 0], w1 = tw[t * 2 + 1];
  float el0 = elbuf[(size_t)(t * 2 + 0) * DM + o];
  float el1 = elbuf[(size_t)(t * 2 + 1) * DM + o];
  was[g][o] = w0 * el0 + w1 * el1;
  __syncthreads();
  float a1 = mb1[o], a2 = mb2[o];
  for (int d = 0; d < DM; ++d) {
    float tt = was[g][d];
    a1 = fmaf(tt, mw1[d * DM + o], a1);
    a2 = fmaf(tt, mw2[d * DM + o], a2);
  }
  float swv = a1 * sigmoid_f(a1) * a2;
  out_x[(size_t)t * DM + o] = xmid[(size_t)t * DM + o] + swv;
  float dd0 = el0 - swv, dd1 = el1 - swv;
  float vt = wave_sum64(w0 * dd0 * dd0 + w1 * dd1 * dd1);
  if ((tid & 63) == 0) wredV[tid >> 6] = vt;
  __syncthreads();
  if (tid < 8)
    out_cons[blockIdx.x * 8 + tid] =
        expf(-(wredV[2 * tid] + wredV[2 * tid + 1]) * (1.0f / 128.0f));
}

extern "C" void kernel_launch(void* const* d_in, const int* in_sizes, int n_in,
                              void* d_out, int out_size, void* d_ws, size_t ws_size,
                              hipStream_t stream) {
  const float* x = (const float*)d_in[0];
  const float* g1 = (const float*)d_in[1];
  const float* wq = (const float*)d_in[2];
  const float* bq = (const float*)d_in[3];
  const float* wk = (const float*)d_in[4];
  const float* bk = (const float*)d_in[5];
  const float* wv = (const float*)d_in[6];
  const float* bv = (const float*)d_in[7];
  const float* wo = (const float*)d_in[8];
  const float* bo = (const float*)d_in[9];
  const float* rot = (const float*)d_in[10];
  const float* tqs = (const float*)d_in[11];
  const float* sw1 = (const float*)d_in[12];
  const float* sb1 = (const float*)d_in[13];
  const float* sw2 = (const float*)d_in[14];
  const float* sb2 = (const float*)d_in[15];
  const float* g2 = (const float*)d_in[16];
  const float* gw = (const float*)d_in[17];
  const float* gb = (const float*)d_in[18];
  const float* ew = (const float*)d_in[19];
  const float* mw1 = (const float*)d_in[20];
  const float* mb1 = (const float*)d_in[21];
  const float* mw2 = (const float*)d_in[22];
  const float* mb2 = (const float*)d_in[23];

  float* ws = (float*)d_ws;
  float* q = ws;                     // 262144
  float* kbuf = ws + 262144;         // 262144
  float* vbuf = ws + 524288;         // 262144
  float* ctxp = ws + 786432;         // 65536
  float* ksump = ws + 851968;        // 4096
  float* xmid = ws + 856064;         // 262144
  float* h2 = ws + 1118208;          // 262144
  float* tw = ws + 1380352;          // 4096
  float* elbuf = ws + 1384448;       // 524288
  int* cnt = (int*)(ws + 1908736);   // 256 ints
  int* list = (int*)(ws + 1908992);  // 256*4096 ints
  float* out_x = (float*)d_out;
  float* out_c = out_x + (size_t)NTOK * DM;

  hipLaunchKernelGGL(k_qkv, dim3(NTOK / 4), dim3(512), 0, stream,
                     x, g1, wq, bq, wk, bk, wv, bv, q, kbuf, vbuf, cnt);
  hipLaunchKernelGGL(k_ctxp, dim3(256), dim3(256), 0, stream, kbuf, vbuf, ctxp, ksump);
  hipLaunchKernelGGL(k_attn, dim3(NTOK / 4), dim3(512), 0, stream,
                     x, q, ctxp, ksump, wo, bo, rot, tqs, sw1, sb1, sw2, sb2, g2,
                     gw, gb, xmid, h2, tw, cnt, list);
  hipLaunchKernelGGL(k_exp, dim3(NE * 2), dim3(512), 0, stream, h2, ew, cnt, list, elbuf);
  hipLaunchKernelGGL(k_comb, dim3(NTOK / 8), dim3(1024), 0, stream,
                     elbuf, tw, xmid, mw1, mb1, mw2, mb2, out_x, out_c);
}